// Round 1
// 911.873 us; speedup vs baseline: 1.1779x; 1.1779x over previous
//
#include <hip/hip_runtime.h>

constexpr int cB  = 4;
constexpr int cN  = 1024;
constexpr int cD  = 768;
constexpr int cH  = 12;
constexpr int cHD = 64;
constexpr int cHID = 3072;
constexpr int cBN = cB * cN;   // 4096 rows

typedef __attribute__((ext_vector_type(8))) short bf16x8;
typedef __attribute__((ext_vector_type(4))) float f32x4;

static __device__ __forceinline__ unsigned short f2bf(float f) {
    union { float f; unsigned int u; } v; v.f = f;
    unsigned int u = v.u;
    return (unsigned short)((u + 0x7FFFu + ((u >> 16) & 1u)) >> 16);
}

static __device__ __forceinline__ void gl_lds16(const void* g, void* l) {
    __builtin_amdgcn_global_load_lds(
        (const __attribute__((address_space(1))) unsigned int*)g,
        (__attribute__((address_space(3))) unsigned int*)l, 16, 0, 0);
}

// ---------------------------------------------------------------------------
// Weight convert: W fp32 [K][N] row-major -> bf16 B-swizzled:
//   elem(n,k) at ((n>>4)*(K/8)+(k>>3))*128 + (n&15)*8 + (k&7)
// ---------------------------------------------------------------------------
__global__ __launch_bounds__(256)
void wconv_kernel(const float* __restrict__ W, unsigned short* __restrict__ Wo,
                  int K, int N) {
    __shared__ float Ls[64][68];
    int k0 = blockIdx.x * 64, n0 = blockIdx.y * 64;
    int t = threadIdx.x;
    int lr = t >> 4, lc = (t & 15) * 4;
    #pragma unroll
    for (int i = 0; i < 4; i++) {
        float4 v = *(const float4*)&W[(size_t)(k0 + lr + i * 16) * N + n0 + lc];
        Ls[lr + i * 16][lc + 0] = v.x;  Ls[lr + i * 16][lc + 1] = v.y;
        Ls[lr + i * 16][lc + 2] = v.z;  Ls[lr + i * 16][lc + 3] = v.w;
    }
    __syncthreads();
    int mt = t >> 3;
    int nb = mt & 3, kb = mt >> 2;
    int sub = t & 7;
    int K8 = K >> 3;
    size_t chunk = ((size_t)(n0 / 16 + nb) * K8 + (size_t)(k0 / 8 + kb)) * 128;
    unsigned short buf[16];
    #pragma unroll
    for (int rr = 0; rr < 2; rr++) {
        int n_r = sub * 2 + rr;
        #pragma unroll
        for (int kk = 0; kk < 8; kk++)
            buf[rr * 8 + kk] = f2bf(Ls[kb * 8 + kk][nb * 16 + n_r]);
    }
    uint4 w0, w1;
    w0.x = buf[0] | ((unsigned)buf[1] << 16);   w0.y = buf[2] | ((unsigned)buf[3] << 16);
    w0.z = buf[4] | ((unsigned)buf[5] << 16);   w0.w = buf[6] | ((unsigned)buf[7] << 16);
    w1.x = buf[8] | ((unsigned)buf[9] << 16);   w1.y = buf[10] | ((unsigned)buf[11] << 16);
    w1.z = buf[12] | ((unsigned)buf[13] << 16); w1.w = buf[14] | ((unsigned)buf[15] << 16);
    *(uint4*)&Wo[chunk + sub * 16]     = w0;
    *(uint4*)&Wo[chunk + sub * 16 + 8] = w1;
}

// ---------------------------------------------------------------------------
// LayerNorm: fp32 in -> bf16 A-swizzled out (K=768 layout).
// ---------------------------------------------------------------------------
__global__ __launch_bounds__(256)
void ln_kernel(const float* __restrict__ x, const float* __restrict__ g,
               const float* __restrict__ b, unsigned short* __restrict__ y) {
    __shared__ float psum[16][17], psq[16][17];
    __shared__ float mean_s[16], rstd_s[16];
    int R = blockIdx.x;
    int t = threadIdx.x;
    int r = t >> 4, c16 = t & 15;
    const float* xr = x + ((size_t)R * 16 + r) * cD;
    float s = 0.f, sq = 0.f;
    #pragma unroll
    for (int i = 0; i < 12; i++) {
        float4 v = *(const float4*)&xr[c16 * 4 + i * 64];
        s  += v.x + v.y + v.z + v.w;
        sq += v.x * v.x + v.y * v.y + v.z * v.z + v.w * v.w;
    }
    psum[r][c16] = s; psq[r][c16] = sq;
    __syncthreads();
    if (t < 16) {
        float ss = 0.f, qq = 0.f;
        #pragma unroll
        for (int i = 0; i < 16; i++) { ss += psum[t][i]; qq += psq[t][i]; }
        float m = ss / (float)cD;
        mean_s[t] = m;
        rstd_s[t] = rsqrtf(qq / (float)cD - m * m + 1e-5f);
    }
    __syncthreads();
    int r2 = t & 15, cslot = t >> 4;
    const float* xr2 = x + ((size_t)R * 16 + r2) * cD;
    float m = mean_s[r2], rs = rstd_s[r2];
    for (int c = cslot; c < 96; c += 16) {
        float4 a0 = *(const float4*)&xr2[c * 8];
        float4 a1 = *(const float4*)&xr2[c * 8 + 4];
        float4 g0 = *(const float4*)&g[c * 8];
        float4 g1 = *(const float4*)&g[c * 8 + 4];
        float4 b0 = *(const float4*)&b[c * 8];
        float4 b1 = *(const float4*)&b[c * 8 + 4];
        unsigned short o[8];
        o[0] = f2bf((a0.x - m) * rs * g0.x + b0.x);
        o[1] = f2bf((a0.y - m) * rs * g0.y + b0.y);
        o[2] = f2bf((a0.z - m) * rs * g0.z + b0.z);
        o[3] = f2bf((a0.w - m) * rs * g0.w + b0.w);
        o[4] = f2bf((a1.x - m) * rs * g1.x + b1.x);
        o[5] = f2bf((a1.y - m) * rs * g1.y + b1.y);
        o[6] = f2bf((a1.z - m) * rs * g1.z + b1.z);
        o[7] = f2bf((a1.w - m) * rs * g1.w + b1.w);
        uint4 w;
        w.x = o[0] | ((unsigned)o[1] << 16); w.y = o[2] | ((unsigned)o[3] << 16);
        w.z = o[4] | ((unsigned)o[5] << 16); w.w = o[6] | ((unsigned)o[7] << 16);
        *(uint4*)&y[((size_t)R * 96 + c) * 128 + r2 * 8] = w;
    }
}

// ---------------------------------------------------------------------------
// MFMA GEMM, single-wave 64x64 blocks, BARRIER-FREE double-buffered pipeline:
// issue next K-step's global_load_lds into buf^1, s_waitcnt vmcnt(8) gates
// current buf, lgkmcnt(0) fences ds-reads before the buffer is reissued.
// modes: 0 row-major bf16 (ostride). 1: A-swizzled + GELU. 2: fp32 + res.
//        3: split: n < vsplit -> row-major bf16 (bias); n >= vsplit -> Vt
//           (biasB[n-vsplit]).  Vt: [b*12+h][d][tok] bf16.
// ---------------------------------------------------------------------------
__global__ __launch_bounds__(64)
void mfma_gemm(const unsigned short* __restrict__ A,
               const unsigned short* __restrict__ Bw,
               const float* __restrict__ bias, const float* __restrict__ biasB,
               const float* __restrict__ res,
               void* __restrict__ Cout, unsigned short* __restrict__ VtOut,
               int K, int N, int ostride, int vsplit, int mode) {
    __shared__ bf16x8 aF[2][4 * 64];
    __shared__ bf16x8 bF[2][4 * 64];
    int l = threadIdx.x;
    int m0 = blockIdx.x * 64, n0 = blockIdx.y * 64;
    int K8 = K >> 3;
    f32x4 acc[4][4];
    #pragma unroll
    for (int i = 0; i < 4; i++)
        #pragma unroll
        for (int j = 0; j < 4; j++) acc[i][j] = (f32x4){0.f, 0.f, 0.f, 0.f};

    const unsigned short* Ab = A  + (size_t)(m0 >> 4) * K8 * 128 + l * 8;
    const unsigned short* Bb = Bw + (size_t)(n0 >> 4) * K8 * 128 + l * 8;

    auto issue = [&](int buf, int k0) {
        int koff = (k0 >> 3) * 128;
        #pragma unroll
        for (int i = 0; i < 4; i++)
            gl_lds16(Ab + (size_t)i * K8 * 128 + koff, &aF[buf][i * 64]);
        #pragma unroll
        for (int i = 0; i < 4; i++)
            gl_lds16(Bb + (size_t)i * K8 * 128 + koff, &bF[buf][i * 64]);
    };

    issue(0, 0);
    int nsteps = K >> 5;
    for (int s = 0; s < nsteps; s++) {
        int cb = s & 1;
        if (s + 1 < nsteps) {
            issue(cb ^ 1, (s + 1) << 5);
            asm volatile("s_waitcnt vmcnt(8)" ::: "memory");
        } else {
            asm volatile("s_waitcnt vmcnt(0)" ::: "memory");
        }
        bf16x8 av[4], bv[4];
        #pragma unroll
        for (int i = 0; i < 4; i++) av[i] = aF[cb][i * 64 + l];
        #pragma unroll
        for (int j = 0; j < 4; j++) bv[j] = bF[cb][j * 64 + l];
        #pragma unroll
        for (int i = 0; i < 4; i++)
            #pragma unroll
            for (int j = 0; j < 4; j++)
                acc[i][j] = __builtin_amdgcn_mfma_f32_16x16x32_bf16(av[i], bv[j], acc[i][j], 0, 0, 0);
        // all ds_reads of buf cb retired before it is reissued next iteration
        asm volatile("s_waitcnt lgkmcnt(0)" ::: "memory");
    }

    int col = l & 15;
    int rb = (l >> 4) * 4;
    if (mode == 2) {
        float* out = (float*)Cout;
        #pragma unroll
        for (int j = 0; j < 4; j++) {
            int n = n0 + j * 16 + col;
            float bj = bias[n];
            #pragma unroll
            for (int i = 0; i < 4; i++)
                #pragma unroll
                for (int r = 0; r < 4; r++) {
                    int mm = m0 + i * 16 + rb + r;
                    out[(size_t)mm * ostride + n] = acc[i][j][r] + bj + res[(size_t)mm * ostride + n];
                }
        }
    } else if (mode == 1) {
        unsigned short* out = (unsigned short*)Cout;
        int N8 = N >> 3;
        #pragma unroll
        for (int j = 0; j < 4; j++) {
            int n = n0 + j * 16 + col;
            float bj = bias[n];
            #pragma unroll
            for (int i = 0; i < 4; i++)
                #pragma unroll
                for (int r = 0; r < 4; r++) {
                    int mm = m0 + i * 16 + rb + r;
                    float v = acc[i][j][r] + bj;
                    v = 0.5f * v * (1.0f + erff(v * 0.70710678118f));
                    size_t ad = ((size_t)(mm >> 4) * N8 + (n >> 3)) * 128 + (mm & 15) * 8 + (n & 7);
                    out[ad] = f2bf(v);
                }
        }
    } else {
        bool toVt = (mode == 3) && (n0 >= vsplit);
        if (!toVt) {
            unsigned short* out = (unsigned short*)Cout;
            #pragma unroll
            for (int j = 0; j < 4; j++) {
                int n = n0 + j * 16 + col;
                float bj = bias[n];
                #pragma unroll
                for (int i = 0; i < 4; i++)
                    #pragma unroll
                    for (int r = 0; r < 4; r++) {
                        int mm = m0 + i * 16 + rb + r;
                        out[(size_t)mm * ostride + n] = f2bf(acc[i][j][r] + bj);
                    }
            }
        } else {
            #pragma unroll
            for (int j = 0; j < 4; j++) {
                int n = n0 + j * 16 + col;
                int vc = n - vsplit;
                float bj = biasB[vc];
                int ph = vc >> 6, d = vc & 63;
                #pragma unroll
                for (int i = 0; i < 4; i++) {
                    int mm = m0 + i * 16 + rb;
                    int bbv = mm >> 10, tok = mm & 1023;
                    unsigned short q0 = f2bf(acc[i][j][0] + bj);
                    unsigned short q1 = f2bf(acc[i][j][1] + bj);
                    unsigned short q2 = f2bf(acc[i][j][2] + bj);
                    unsigned short q3 = f2bf(acc[i][j][3] + bj);
                    uint2 pk;
                    pk.x = q0 | ((unsigned)q1 << 16);
                    pk.y = q2 | ((unsigned)q3 << 16);
                    size_t ad = ((size_t)(bbv * 12 + ph) * 64 + d) * 1024 + tok;
                    *(uint2*)&VtOut[ad] = pk;
                }
            }
        }
    }
}

// ---------------------------------------------------------------------------
// MFMA flash attention. 4 waves/block share one (b,h); K/V tiles staged in
// LDS via global_load_lds (zero VGPR cost, 4x traffic dedup), double-buffered
// with counted vmcnt(4) so next tile's DMA flies under current tile's
// softmax+MFMA. Source-side 16B-chunk XOR swizzle (chunk ^= row&7) keeps the
// ds_read_b128 fragment reads at the minimal 8-phase pattern.
// ---------------------------------------------------------------------------
__global__ __launch_bounds__(256, 2)
void fattn_kernel(const unsigned short* __restrict__ Qp,
                  const unsigned short* __restrict__ Kp,
                  const unsigned short* __restrict__ Vt,
                  unsigned short* __restrict__ O,
                  int qk_stride, float scale) {
    __shared__ unsigned short Kls[2][4096];   // [64 keys][64 dims], swizzled
    __shared__ unsigned short Vls[2][4096];   // [64 dims][64 toks], swizzled
    __shared__ unsigned short Ps[4][16][72];

    int t = threadIdx.x;
    int w = t >> 6, l = t & 63;
    int la = l & 15, lb = l >> 4;
    int swz = la & 7;
    int blk = blockIdx.x;
    int qt0 = (blk & 15) * 64 + w * 16;
    int bh = blk >> 4;
    int h = bh % cH, bb = bh / cH;

    const unsigned short* Qb = Qp + (size_t)(bb * cN) * qk_stride + h * cHD;
    const unsigned short* Kb = Kp + (size_t)(bb * cN) * qk_stride + h * cHD;
    const unsigned short* Vb = Vt + (size_t)(bb * cH + h) * (64 * 1024);

    bf16x8 av[2];
    #pragma unroll
    for (int s = 0; s < 2; s++)
        av[s] = *(const bf16x8*)(Qb + (size_t)(qt0 + la) * qk_stride + 32 * s + 8 * lb);

    // ---- staging geometry: 512 chunks of 16B per 8KB tile, 2 chunks/thread.
    // LDS slot (row r, chunk c) holds global chunk (r, c ^ (r&7)).
    int ch0 = w * 128 + l;
    int ch1 = ch0 + 64;
    int r0 = ch0 >> 3, c0 = (ch0 & 7) ^ (r0 & 7);
    int r1 = ch1 >> 3, c1 = (ch1 & 7) ^ (r1 & 7);
    const unsigned short* K0 = Kb + (size_t)r0 * qk_stride + c0 * 8;
    const unsigned short* K1 = Kb + (size_t)r1 * qk_stride + c1 * 8;
    const unsigned short* V0 = Vb + (size_t)r0 * 1024 + c0 * 8;
    const unsigned short* V1 = Vb + (size_t)r1 * 1024 + c1 * 8;
    int dst0 = w * 1024;        // elems: (w*128)*8
    int dst1 = dst0 + 512;      // elems: (w*128+64)*8

    auto stage = [&](int buf, int kt0) {
        gl_lds16(K0 + (size_t)kt0 * qk_stride, &Kls[buf][dst0]);
        gl_lds16(K1 + (size_t)kt0 * qk_stride, &Kls[buf][dst1]);
        gl_lds16(V0 + kt0, &Vls[buf][dst0]);
        gl_lds16(V1 + kt0, &Vls[buf][dst1]);
    };

    float m_run[4], l_run[4];
    f32x4 acc_o[4];
    #pragma unroll
    for (int r = 0; r < 4; r++) { m_run[r] = -1e30f; l_run[r] = 0.f; }
    #pragma unroll
    for (int nt = 0; nt < 4; nt++) acc_o[nt] = (f32x4){0.f, 0.f, 0.f, 0.f};

    stage(0, 0);
    for (int it = 0; it < 16; it++) {
        int cb = it & 1;
        if (it < 15) {
            stage(cb ^ 1, (it + 1) << 6);
            asm volatile("s_waitcnt vmcnt(4)" ::: "memory");   // cur tile landed
        } else {
            asm volatile("s_waitcnt vmcnt(0)" ::: "memory");
        }
        __builtin_amdgcn_s_barrier();
        asm volatile("" ::: "memory");

        // ---- K frags from LDS
        bf16x8 kf[4][2];
        #pragma unroll
        for (int j = 0; j < 4; j++)
            #pragma unroll
            for (int s = 0; s < 2; s++)
                kf[j][s] = *(const bf16x8*)&Kls[cb][(16 * j + la) * 64 + (((4 * s + lb) ^ swz) << 3)];

        // ---- S = Q K^T
        f32x4 sj[4];
        #pragma unroll
        for (int j = 0; j < 4; j++) sj[j] = (f32x4){0.f, 0.f, 0.f, 0.f};
        #pragma unroll
        for (int j = 0; j < 4; j++)
            #pragma unroll
            for (int s = 0; s < 2; s++)
                sj[j] = __builtin_amdgcn_mfma_f32_16x16x32_bf16(av[s], kf[j][s], sj[j], 0, 0, 0);

        // ---- online softmax in registers
        float x[4][4];
        #pragma unroll
        for (int j = 0; j < 4; j++)
            #pragma unroll
            for (int r = 0; r < 4; r++) x[j][r] = sj[j][r] * scale;
        float mt[4];
        #pragma unroll
        for (int r = 0; r < 4; r++)
            mt[r] = fmaxf(fmaxf(x[0][r], x[1][r]), fmaxf(x[2][r], x[3][r]));
        #pragma unroll
        for (int off = 1; off <= 8; off <<= 1)
            #pragma unroll
            for (int r = 0; r < 4; r++)
                mt[r] = fmaxf(mt[r], __shfl_xor(mt[r], off, 64));
        float al[4];
        #pragma unroll
        for (int r = 0; r < 4; r++) {
            float mn = fmaxf(m_run[r], mt[r]);
            al[r] = __expf(m_run[r] - mn);
            m_run[r] = mn;
        }
        float p[4][4], ts[4] = {0.f, 0.f, 0.f, 0.f};
        #pragma unroll
        for (int j = 0; j < 4; j++)
            #pragma unroll
            for (int r = 0; r < 4; r++) {
                p[j][r] = __expf(x[j][r] - m_run[r]);
                ts[r] += p[j][r];
            }
        #pragma unroll
        for (int off = 1; off <= 8; off <<= 1)
            #pragma unroll
            for (int r = 0; r < 4; r++)
                ts[r] += __shfl_xor(ts[r], off, 64);
        #pragma unroll
        for (int r = 0; r < 4; r++) l_run[r] = l_run[r] * al[r] + ts[r];
        #pragma unroll
        for (int nt = 0; nt < 4; nt++)
            #pragma unroll
            for (int r = 0; r < 4; r++) acc_o[nt][r] *= al[r];

        // ---- P: C-layout regs -> wave-private LDS -> A-frags
        #pragma unroll
        for (int j = 0; j < 4; j++)
            #pragma unroll
            for (int r = 0; r < 4; r++)
                Ps[w][lb * 4 + r][16 * j + la] = f2bf(p[j][r]);
        asm volatile("s_waitcnt lgkmcnt(0)" ::: "memory");
        bf16x8 pf[2];
        #pragma unroll
        for (int s = 0; s < 2; s++)
            pf[s] = *(const bf16x8*)&Ps[w][la][32 * s + 8 * lb];

        // ---- V frags from LDS, O += P V
        bf16x8 vf[4][2];
        #pragma unroll
        for (int nt = 0; nt < 4; nt++)
            #pragma unroll
            for (int s = 0; s < 2; s++)
                vf[nt][s] = *(const bf16x8*)&Vls[cb][(16 * nt + la) * 64 + (((4 * s + lb) ^ swz) << 3)];
        #pragma unroll
        for (int nt = 0; nt < 4; nt++)
            #pragma unroll
            for (int s = 0; s < 2; s++)
                acc_o[nt] = __builtin_amdgcn_mfma_f32_16x16x32_bf16(pf[s], vf[nt][s], acc_o[nt], 0, 0, 0);

        // drain ds_reads so next iteration's restage of buf cb can't race them
        asm volatile("s_waitcnt lgkmcnt(0)" ::: "memory");
        __builtin_amdgcn_s_barrier();
    }

    // ---- epilogue: O/l, A-swizzled store (K=768 layout)
    float inv[4];
    #pragma unroll
    for (int r = 0; r < 4; r++) inv[r] = 1.0f / l_run[r];
    size_t mhi = ((size_t)bb * cN + qt0) >> 4;
    #pragma unroll
    for (int nt = 0; nt < 4; nt++) {
        int k = h * cHD + 16 * nt + la;
        size_t base = (mhi * 96 + (k >> 3)) * 128 + (k & 7);
        #pragma unroll
        for (int r = 0; r < 4; r++) {
            unsigned short val = f2bf(acc_o[nt][r] * inv[r]);
            O[base + (lb * 4 + r) * 8] = val;
        }
    }
}

// ---------------------------------------------------------------------------
extern "C" void kernel_launch(void* const* d_in, const int* in_sizes, int n_in,
                              void* d_out, int out_size, void* d_ws, size_t ws_size,
                              hipStream_t stream) {
    const float* img_tok  = (const float*)d_in[0];
    const float* evt_tok  = (const float*)d_in[1];
    const float* ln_q1_g  = (const float*)d_in[2];
    const float* ln_q1_b  = (const float*)d_in[3];
    const float* ln_kv1_g = (const float*)d_in[4];
    const float* ln_kv1_b = (const float*)d_in[5];
    const float* ln_q2_g  = (const float*)d_in[6];
    const float* ln_q2_b  = (const float*)d_in[7];
    const float* ln_kv2_g = (const float*)d_in[8];
    const float* ln_kv2_b = (const float*)d_in[9];
    const float* ln_mi_g  = (const float*)d_in[10];
    const float* ln_mi_b  = (const float*)d_in[11];
    const float* ln_me_g  = (const float*)d_in[12];
    const float* ln_me_b  = (const float*)d_in[13];
    const float* si_qkv_w  = (const float*)d_in[14];
    const float* si_qkv_b  = (const float*)d_in[15];
    const float* si_proj_w = (const float*)d_in[16];
    const float* si_proj_b = (const float*)d_in[17];
    const float* se_qkv_w  = (const float*)d_in[18];
    const float* se_qkv_b  = (const float*)d_in[19];
    const float* se_proj_w = (const float*)d_in[20];
    const float* se_proj_b = (const float*)d_in[21];
    const float* xei_q_w = (const float*)d_in[22];
    const float* xei_q_b = (const float*)d_in[23];
    const float* xei_k_w = (const float*)d_in[24];
    const float* xei_k_b = (const float*)d_in[25];
    const float* xei_v_w = (const float*)d_in[26];
    const float* xei_v_b = (const float*)d_in[27];
    const float* xei_p_w = (const float*)d_in[28];
    const float* xei_p_b = (const float*)d_in[29];
    const float* xie_q_w = (const float*)d_in[30];
    const float* xie_q_b = (const float*)d_in[31];
    const float* xie_k_w = (const float*)d_in[32];
    const float* xie_k_b = (const float*)d_in[33];
    const float* xie_v_w = (const float*)d_in[34];
    const float* xie_v_b = (const float*)d_in[35];
    const float* xie_p_w = (const float*)d_in[36];
    const float* xie_p_b = (const float*)d_in[37];
    const float* mi_fc1_w = (const float*)d_in[38];
    const float* mi_fc1_b = (const float*)d_in[39];
    const float* mi_fc2_w = (const float*)d_in[40];
    const float* mi_fc2_b = (const float*)d_in[41];
    const float* me_fc1_w = (const float*)d_in[42];
    const float* me_fc1_b = (const float*)d_in[43];
    const float* me_fc2_w = (const float*)d_in[44];
    const float* me_fc2_b = (const float*)d_in[45];

    const size_t U = (size_t)cBN * cD;               // 3,145,728
    unsigned short* wsb = (unsigned short*)d_ws;
    unsigned short* Wz  = wsb;                       // 18,874,368 elems
    unsigned short* LNo = wsb + 18874368;            // U
    unsigned short* AO  = LNo + U;                   // U
    unsigned short* T1  = AO + U;                    // 3U (row stride 2304)
    unsigned short* Vt  = T1 + 3 * U;                // U  [48][64][1024]
    unsigned short* Hid = AO;                        // 4U alias (AO + T1)
    float* out_img = (float*)d_out;
    float* out_evt = out_img + U;

    // weight offsets (bf16 elems); 768x768 = 589824
    const size_t O_SI_QKV = 0,        O_SE_QKV = 1769472;
    const size_t O_SI_P   = 3538944,  O_SE_P   = 4128768;
    const size_t O_XEI_Q  = 4718592,  O_XEI_KV = 5308416, O_XEI_P = 6488064;
    const size_t O_XIE_Q  = 7077888,  O_XIE_KV = 7667712, O_XIE_P = 8847360;
    const size_t O_MI_F1  = 9437184,  O_MI_F2  = 11796480;
    const size_t O_ME_F1  = 14155776, O_ME_F2  = 16515072;

    auto wc = [&](const float* w, size_t off, int K, int N) {
        hipLaunchKernelGGL(wconv_kernel, dim3(K / 64, N / 64), dim3(256), 0, stream,
                           w, Wz + off, K, N);
    };
    auto ln = [&](const float* x_, const float* g_, const float* b_, unsigned short* y_) {
        hipLaunchKernelGGL(ln_kernel, dim3(cBN / 16), dim3(256), 0, stream, x_, g_, b_, y_);
    };
    auto gemm = [&](const unsigned short* A_, size_t woff, const float* b_, const float* bB_,
                    const float* r_, void* C_, int K_, int N_, int ostride_, int vsplit_, int mode_) {
        hipLaunchKernelGGL(mfma_gemm, dim3(cBN / 64, N_ / 64), dim3(64), 0, stream,
                           A_, Wz + woff, b_, bB_, r_, C_, Vt, K_, N_, ostride_, vsplit_, mode_);
    };
    auto attn = [&](const unsigned short* q_, const unsigned short* k_,
                    unsigned short* o_, float sc_) {
        hipLaunchKernelGGL(fattn_kernel, dim3(cB * cH * 16), dim3(256), 0, stream,
                           q_, k_, Vt, o_, 2304, sc_);
    };
    const float SC = 0.125f;

    // ---- weight conversion
    wc(si_qkv_w, O_SI_QKV, 768, 2304);  wc(se_qkv_w, O_SE_QKV, 768, 2304);
    wc(si_proj_w, O_SI_P, 768, 768);    wc(se_proj_w, O_SE_P, 768, 768);
    wc(xei_q_w, O_XEI_Q, 768, 768);
    wc(xei_k_w, O_XEI_KV, 768, 768);    wc(xei_v_w, O_XEI_KV + 589824, 768, 768);
    wc(xei_p_w, O_XEI_P, 768, 768);
    wc(xie_q_w, O_XIE_Q, 768, 768);
    wc(xie_k_w, O_XIE_KV, 768, 768);    wc(xie_v_w, O_XIE_KV + 589824, 768, 768);
    wc(xie_p_w, O_XIE_P, 768, 768);
    wc(mi_fc1_w, O_MI_F1, 768, 3072);   wc(mi_fc2_w, O_MI_F2, 3072, 768);
    wc(me_fc1_w, O_ME_F1, 768, 3072);   wc(me_fc2_w, O_ME_F2, 3072, 768);

    // ---- self-attn img
    ln(img_tok, ln_q1_g, ln_q1_b, LNo);
    gemm(LNo, O_SI_QKV, si_qkv_b, si_qkv_b + 1536, nullptr, T1, 768, 2304, 2304, 1536, 3);
    attn(T1, T1 + 768, AO, SC);
    gemm(AO, O_SI_P, si_proj_b, nullptr, img_tok, out_img, 768, 768, 768, 0, 2);

    // ---- self-attn evt
    ln(evt_tok, ln_kv1_g, ln_kv1_b, LNo);
    gemm(LNo, O_SE_QKV, se_qkv_b, se_qkv_b + 1536, nullptr, T1, 768, 2304, 2304, 1536, 3);
    attn(T1, T1 + 768, AO, SC);
    gemm(AO, O_SE_P, se_proj_b, nullptr, evt_tok, out_evt, 768, 768, 768, 0, 2);

    // ---- cross xei: q=ln_q2(i1), kv=ln_kv2(e1), negated
    ln(out_img, ln_q2_g, ln_q2_b, LNo);
    gemm(LNo, O_XEI_Q, xei_q_b, nullptr, nullptr, T1, 768, 768, 2304, 1 << 30, 0);
    ln(out_evt, ln_kv2_g, ln_kv2_b, LNo);
    gemm(LNo, O_XEI_KV, xei_k_b, xei_v_b, nullptr, T1 + 768, 768, 1536, 2304, 768, 3);
    attn(T1, T1 + 768, AO, -SC);

    // ---- xie inputs while i1/e1 intact (xei attn already consumed T1/Vt)
    ln(out_img, ln_kv2_g, ln_kv2_b, LNo);
    gemm(LNo, O_XIE_KV, xie_k_b, xie_v_b, nullptr, T1 + 768, 768, 1536, 2304, 768, 3);
    ln(out_evt, ln_q2_g, ln_q2_b, LNo);
    gemm(LNo, O_XIE_Q, xie_q_b, nullptr, nullptr, T1, 768, 768, 2304, 1 << 30, 0);

    gemm(AO, O_XEI_P, xei_p_b, nullptr, out_img, out_img, 768, 768, 768, 0, 2);   // i2
    attn(T1, T1 + 768, AO, -SC);
    gemm(AO, O_XIE_P, xie_p_b, nullptr, out_evt, out_evt, 768, 768, 768, 0, 2);   // e2

    // ---- MLP img
    ln(out_img, ln_mi_g, ln_mi_b, LNo);
    gemm(LNo, O_MI_F1, mi_fc1_b, nullptr, nullptr, Hid, 768, 3072, 3072, 0, 1);
    gemm(Hid, O_MI_F2, mi_fc2_b, nullptr, out_img, out_img, 3072, 768, 768, 0, 2);

    // ---- MLP evt
    ln(out_evt, ln_me_g, ln_me_b, LNo);
    gemm(LNo, O_ME_F1, me_fc1_b, nullptr, nullptr, Hid, 768, 3072, 3072, 0, 1);
    gemm(Hid, O_ME_F2, me_fc2_b, nullptr, out_evt, out_evt, 3072, 768, 768, 0, 2);
}